// Round 11
// baseline (179.398 us; speedup 1.0000x reference)
//
#include <hip/hip_runtime.h>
#include <hip/hip_bf16.h>
#include <stdint.h>

#define NTOK 8192
#define D_   1024
#define E_   8
#define MT   128
#define NT   128
#define BK   64
#define KSTEPS 16
#define MAX_TILES 160
#define SLOTS (NTOK * 2)

typedef __attribute__((ext_vector_type(8))) short short8;
typedef __attribute__((ext_vector_type(4))) float f32x4;

__device__ inline unsigned short f2b(float f) {
    unsigned int u = __float_as_uint(f);
    unsigned int r = (u + 0x7fffu + ((u >> 16) & 1u)) >> 16;
    return (unsigned short)r;
}

// async global->LDS, 16B per lane; LDS dest = wave-uniform base + lane*16.
__device__ inline void gload16(const void* g, void* l) {
    __builtin_amdgcn_global_load_lds(
        (const __attribute__((address_space(1))) unsigned int*)(uintptr_t)g,
        (__attribute__((address_space(3))) unsigned int*)(unsigned int)(uintptr_t)l,
        16, 0, 0);
}

// ---- Phase 0+1 fused: gate+cast (0..1023) || We transpose (1024..3071) || zero out (3072..3583) ----
__global__ __launch_bounds__(256) void prep_kernel(const float* __restrict__ We,
                                                   unsigned short* __restrict__ WeT,
                                                   const float* __restrict__ x,
                                                   const float* __restrict__ Wg,
                                                   int2* __restrict__ e2,
                                                   float2* __restrict__ w2,
                                                   unsigned short* __restrict__ Abf,
                                                   float* __restrict__ out) {
    __shared__ __align__(16) float smem[8192];   // overlay: 8x1024 wgt | 64x65 tile
    int b = blockIdx.x;
    int t = threadIdx.x;
    if (b < 1024) {
        // ---- gating + unweighted bf16 cast; 8 tokens per block, 2 per wave ----
        float* wgt = smem;   // transposed: wgt[e*1024 + d]
        for (int i = t; i < 8192; i += 256) wgt[(i & 7) * 1024 + (i >> 3)] = Wg[i];
        __syncthreads();
        int wave = t >> 6, lane = t & 63;
        int tok0 = b * 8 + wave * 2;

        for (int tki = 0; tki < 2; tki++) {
            int tok = tok0 + tki;
            const float* xr = x + (size_t)tok * D_;

            float4 xv[4];
            float acc[8] = {0.f, 0.f, 0.f, 0.f, 0.f, 0.f, 0.f, 0.f};
            #pragma unroll
            for (int i = 0; i < 4; i++) {
                int d0 = i * 256 + lane * 4;
                xv[i] = *reinterpret_cast<const float4*>(xr + d0);
                #pragma unroll
                for (int e = 0; e < 8; e++) {
                    float4 w = *reinterpret_cast<const float4*>(&wgt[e * 1024 + d0]);
                    acc[e] += xv[i].x * w.x + xv[i].y * w.y + xv[i].z * w.z + xv[i].w * w.w;
                }
            }
            #pragma unroll
            for (int e = 0; e < 8; e++)
                #pragma unroll
                for (int off = 32; off > 0; off >>= 1)
                    acc[e] += __shfl_xor(acc[e], off, 64);

            float best = acc[0]; int bi = 0;
            #pragma unroll
            for (int e = 1; e < 8; e++) { if (acc[e] > best) { best = acc[e]; bi = e; } }
            float second = -3.4e38f; int si = 0;
            #pragma unroll
            for (int e = 0; e < 8; e++) { if (e != bi && acc[e] > second) { second = acc[e]; si = e; } }
            float eb = __expf(second - best);
            eb = fmaxf(eb, 1e-20f);
            float w0 = 1.f / (1.f + eb);   // weight of best
            float w1 = eb / (1.f + eb);    // weight of second
            if (lane == 0) {
                e2[tok] = make_int2(bi, si);
                w2[tok] = make_float2(w0, w1);
            }

            unsigned short* rowp = Abf + (size_t)tok * D_;
            #pragma unroll
            for (int i = 0; i < 4; i++) {
                int d0 = i * 256 + lane * 4;
                uint2 p;
                p.x = (unsigned)f2b(xv[i].x) | ((unsigned)f2b(xv[i].y) << 16);
                p.y = (unsigned)f2b(xv[i].z) | ((unsigned)f2b(xv[i].w) << 16);
                *reinterpret_cast<uint2*>(rowp + d0) = p;
            }
        }
    } else if (b < 3072) {
        // ---- We (E,D,D) f32 -> WeT (E,M,D) bf16 ----
        float (*tile)[65] = reinterpret_cast<float (*)[65]>(smem);
        int bb = b - 1024;
        int e = bb >> 8, rem = bb & 255;
        int m0 = (rem & 15) * 64, d0 = (rem >> 4) * 64;
        const float* src = We + ((size_t)e << 20);
        int r = t >> 4, c4 = (t & 15) * 4;
        #pragma unroll
        for (int i = 0; i < 4; i++) {
            int d = r + i * 16;
            float4 v = *reinterpret_cast<const float4*>(src + (size_t)(d0 + d) * D_ + m0 + c4);
            tile[d][c4 + 0] = v.x; tile[d][c4 + 1] = v.y;
            tile[d][c4 + 2] = v.z; tile[d][c4 + 3] = v.w;
        }
        __syncthreads();
        int m = t >> 2, dq = (t & 3) * 16;
        unsigned int pack[8];
        #pragma unroll
        for (int j = 0; j < 16; j += 2) {
            pack[j >> 1] = (unsigned int)f2b(tile[dq + j][m]) |
                           ((unsigned int)f2b(tile[dq + j + 1][m]) << 16);
        }
        uint4* dst = reinterpret_cast<uint4*>(WeT + ((size_t)e << 20) + (size_t)(m0 + m) * D_ + d0 + dq);
        dst[0] = make_uint4(pack[0], pack[1], pack[2], pack[3]);
        dst[1] = make_uint4(pack[4], pack[5], pack[6], pack[7]);
    } else {
        // ---- zero the output (atomics accumulate into it) ----
        float4 z = make_float4(0.f, 0.f, 0.f, 0.f);
        float4* o4 = reinterpret_cast<float4*>(out) + (size_t)(b - 3072) * 4096 + t;
        #pragma unroll
        for (int i = 0; i < 16; i++) o4[i * 256] = z;
    }
}

// ---------------- Phase 2: routing — per-expert buckets, 8 blocks, mixed 128/64 tiles ----------------
__global__ __launch_bounds__(256) void route_kernel(const int2* __restrict__ e2,
                                                    const float2* __restrict__ w2,
                                                    int* __restrict__ token_list,
                                                    float* __restrict__ w_s,
                                                    int4* __restrict__ tile_desc,
                                                    int* __restrict__ n_tiles_out) {
    int g = blockIdx.x;    // expert 0..7
    int t = threadIdx.x;   // 0..255
    __shared__ int cnt[8];
    __shared__ int pfx[256];
    __shared__ int startg, tbase, tottiles;
    if (t < 8) cnt[t] = 0;
    __syncthreads();

    int base = t * 32;
    int my = 0;
    for (int k = 0; k < 32; k++) {
        int2 e = e2[base + k];
        my += (e.x == g) + (e.y == g);
        atomicAdd(&cnt[e.x], 1);
        atomicAdd(&cnt[e.y], 1);
    }
    pfx[t] = my;
    __syncthreads();

    if (t == 0) {
        int run = 0, tb = 0, tt = 0;
        for (int gg = 0; gg < 8; gg++) {
            int c = cnt[gg];
            int n = 0, rem = c;
            while (rem > 64) { int take = (rem >= 128) ? 128 : rem; rem -= take; n++; }
            if (rem > 0) n++;
            if (gg < g) { run += c; tb += n; }
            tt += n;
        }
        startg = run; tbase = tb; tottiles = tt;
    }
    for (int off = 1; off < 256; off <<= 1) {
        int add = (t >= off) ? pfx[t - off] : 0;
        __syncthreads();
        pfx[t] += add;
        __syncthreads();
    }

    int pos = startg + pfx[t] - my;
    for (int k = 0; k < 32; k++) {
        int idx = base + k;
        int2 e = e2[idx];
        float2 w = w2[idx];
        if (e.x == g) { token_list[pos] = idx; w_s[pos] = w.x; pos++; }
        if (e.y == g) { token_list[pos] = idx; w_s[pos] = w.y; pos++; }
    }
    if (t == 0) {
        int rem = cnt[g], off2 = 0, ti = tbase;
        while (rem > 64) {
            int take = (rem >= 128) ? 128 : rem;
            tile_desc[ti++] = make_int4(startg + off2, take, g, 0);
            off2 += take; rem -= take;
        }
        if (rem > 0) tile_desc[ti++] = make_int4(startg + off2, rem, g, 0);
        if (g == 0) *n_tiles_out = tottiles;
    }
}

// ---------------- Phase 3: grouped GEMM — per-expert tiles, K=1024, epilogue f32 atomicAdd ----------------
// Grid dim3(8, tiles): XCD = colblk -> per-XCD B slice = 2 MB (L2-resident).
// Each out element receives exactly 2 atomic adds (commutative -> deterministic); out pre-zeroed.
__global__ __launch_bounds__(256, 4) void moe_gemm(const unsigned short* __restrict__ Abf,
                                                   const unsigned short* __restrict__ WeT,
                                                   const int* __restrict__ token_list,
                                                   const float* __restrict__ w_s,
                                                   const int4* __restrict__ tile_desc,
                                                   const int* __restrict__ n_tiles,
                                                   float* __restrict__ out) {
    int tile = blockIdx.y;
    if (tile >= *n_tiles) return;
    int4 dsc = tile_desc[tile];
    int loff = dsc.x, rows = dsc.y, e = dsc.z;
    int ncol0 = blockIdx.x * NT;

    __shared__ __align__(16) unsigned short As[MT * BK];   // 16 KB
    __shared__ __align__(16) unsigned short Bs[NT * BK];   // 16 KB
    __shared__ int tokOut[MT];
    __shared__ int tokStage[MT];
    __shared__ float wsh[MT];

    int t = threadIdx.x;
    int wave = t >> 6, lane = t & 63;

    if (t < MT) {
        int idx = loff + ((t < rows) ? t : 0);
        int tk = token_list[idx];
        tokStage[t] = tk;
        tokOut[t] = (t < rows) ? tk : -1;
        wsh[t] = w_s[idx];
    }
    __syncthreads();

    const unsigned short* wbase = WeT + ((size_t)e << 20);
    int l15 = lane & 15, hi = lane >> 4, q4 = hi * 4;

    if (rows > 64) {
        // ================= FULL PATH: 128x128, wave-tile 64x64 =================
        const unsigned short* asrc[4];
        const unsigned short* bsrc[4];
        #pragma unroll
        for (int i = 0; i < 4; i++) {
            int g = t + i * 256;
            int row = g >> 3;
            int c = (g & 7) ^ (row & 7);
            asrc[i] = Abf + (size_t)tokStage[row] * D_ + c * 8;
            bsrc[i] = wbase + (size_t)(ncol0 + row) * D_ + c * 8;
        }

        int wm = (wave >> 1) * 64, wn = (wave & 1) * 64;
        int aoff[2][4], boff[2][4];
        #pragma unroll
        for (int ksub = 0; ksub < 2; ksub++) {
            #pragma unroll
            for (int m = 0; m < 4; m++) {
                int r = wm + m * 16 + l15;
                aoff[ksub][m] = r * BK + (((hi + 4 * ksub) ^ (r & 7)) << 3);
                int rb = wn + m * 16 + l15;
                boff[ksub][m] = rb * BK + (((hi + 4 * ksub) ^ (rb & 7)) << 3);
            }
        }

        f32x4 acc[4][4];
        #pragma unroll
        for (int m = 0; m < 4; m++)
            #pragma unroll
            for (int n = 0; n < 4; n++) acc[m][n] = (f32x4){0.f, 0.f, 0.f, 0.f};

        for (int ks = 0; ks < KSTEPS; ++ks) {
            int k0 = ks * BK;
            #pragma unroll
            for (int i = 0; i < 4; i++) {
                int dbase = (i * 256 + wave * 64) * 8;
                gload16(asrc[i] + k0, As + dbase);
                gload16(bsrc[i] + k0, Bs + dbase);
            }
            asm volatile("s_waitcnt vmcnt(0)" ::: "memory");
            __builtin_amdgcn_s_barrier();
            #pragma unroll
            for (int ksub = 0; ksub < 2; ++ksub) {
                short8 a[4], bfr[4];
                #pragma unroll
                for (int m = 0; m < 4; m++) {
                    a[m] = *reinterpret_cast<const short8*>(&As[aoff[ksub][m]]);
                    bfr[m] = *reinterpret_cast<const short8*>(&Bs[boff[ksub][m]]);
                }
                #pragma unroll
                for (int m = 0; m < 4; m++)
                    #pragma unroll
                    for (int n = 0; n < 4; n++)
                        acc[m][n] = __builtin_amdgcn_mfma_f32_16x16x32_bf16(a[m], bfr[n], acc[m][n], 0, 0, 0);
            }
            __builtin_amdgcn_s_barrier();
        }

        #pragma unroll
        for (int m = 0; m < 4; m++) {
            #pragma unroll
            for (int n = 0; n < 4; n++) {
                int col = ncol0 + wn + n * 16 + l15;
                #pragma unroll
                for (int j = 0; j < 4; j++) {
                    int r = wm + m * 16 + q4 + j;
                    int tk = tokOut[r];
                    if (tk >= 0) unsafeAtomicAdd(&out[(size_t)tk * D_ + col], acc[m][n][j] * wsh[r]);
                }
            }
        }
    } else {
        // ================= TAIL PATH: 64x128, wave-tile 32x64 =================
        const unsigned short* asrcT[2];
        const unsigned short* bsrcT[4];
        #pragma unroll
        for (int i = 0; i < 2; i++) {
            int g = t + i * 256;
            int row = g >> 3;
            int c = (g & 7) ^ (row & 7);
            asrcT[i] = Abf + (size_t)tokStage[row] * D_ + c * 8;
        }
        #pragma unroll
        for (int i = 0; i < 4; i++) {
            int g = t + i * 256;
            int row = g >> 3;
            int c = (g & 7) ^ (row & 7);
            bsrcT[i] = wbase + (size_t)(ncol0 + row) * D_ + c * 8;
        }

        int wm = (wave >> 1) * 32, wn = (wave & 1) * 64;
        int aoff[2][2], boff[2][4];
        #pragma unroll
        for (int ksub = 0; ksub < 2; ksub++) {
            #pragma unroll
            for (int m = 0; m < 2; m++) {
                int r = wm + m * 16 + l15;
                aoff[ksub][m] = r * BK + (((hi + 4 * ksub) ^ (r & 7)) << 3);
            }
            #pragma unroll
            for (int n = 0; n < 4; n++) {
                int rb = wn + n * 16 + l15;
                boff[ksub][n] = rb * BK + (((hi + 4 * ksub) ^ (rb & 7)) << 3);
            }
        }

        f32x4 acc[2][4];
        #pragma unroll
        for (int m = 0; m < 2; m++)
            #pragma unroll
            for (int n = 0; n < 4; n++) acc[m][n] = (f32x4){0.f, 0.f, 0.f, 0.f};

        for (int ks = 0; ks < KSTEPS; ++ks) {
            int k0 = ks * BK;
            #pragma unroll
            for (int i = 0; i < 2; i++)
                gload16(asrcT[i] + k0, As + (i * 256 + wave * 64) * 8);
            #pragma unroll
            for (int i = 0; i < 4; i++)
                gload16(bsrcT[i] + k0, Bs + (i * 256 + wave * 64) * 8);
            asm volatile("s_waitcnt vmcnt(0)" ::: "memory");
            __builtin_amdgcn_s_barrier();
            #pragma unroll
            for (int ksub = 0; ksub < 2; ++ksub) {
                short8 a[2], bfr[4];
                #pragma unroll
                for (int m = 0; m < 2; m++)
                    a[m] = *reinterpret_cast<const short8*>(&As[aoff[ksub][m]]);
                #pragma unroll
                for (int n = 0; n < 4; n++)
                    bfr[n] = *reinterpret_cast<const short8*>(&Bs[boff[ksub][n]]);
                #pragma unroll
                for (int m = 0; m < 2; m++)
                    #pragma unroll
                    for (int n = 0; n < 4; n++)
                        acc[m][n] = __builtin_amdgcn_mfma_f32_16x16x32_bf16(a[m], bfr[n], acc[m][n], 0, 0, 0);
            }
            __builtin_amdgcn_s_barrier();
        }

        #pragma unroll
        for (int m = 0; m < 2; m++) {
            #pragma unroll
            for (int n = 0; n < 4; n++) {
                int col = ncol0 + wn + n * 16 + l15;
                #pragma unroll
                for (int j = 0; j < 4; j++) {
                    int r = wm + m * 16 + q4 + j;
                    int tk = tokOut[r];
                    if (tk >= 0) unsafeAtomicAdd(&out[(size_t)tk * D_ + col], acc[m][n][j] * wsh[r]);
                }
            }
        }
    }
}

extern "C" void kernel_launch(void* const* d_in, const int* in_sizes, int n_in,
                              void* d_out, int out_size, void* d_ws, size_t ws_size,
                              hipStream_t stream) {
    const float* x  = (const float*)d_in[0];
    const float* Wg = (const float*)d_in[1];
    const float* We = (const float*)d_in[2];
    float* out = (float*)d_out;

    size_t off = 0;
    auto alloc = [&](size_t bytes) -> void* {
        void* p = (char*)d_ws + off;
        off += (bytes + 255) & ~(size_t)255;
        return p;
    };
    unsigned short* WeT  = (unsigned short*)alloc((size_t)E_ * 1024 * 1024 * 2);  // 16 MB
    unsigned short* Abf  = (unsigned short*)alloc((size_t)NTOK * D_ * 2);         // 16.8 MB
    int2*   e2        = (int2*)  alloc(NTOK * 8);
    float2* w2        = (float2*)alloc(NTOK * 8);
    int*    token_list= (int*)   alloc(SLOTS * 4);
    float*  w_s       = (float*) alloc(SLOTS * 4);
    int4*   tile_desc = (int4*)  alloc(MAX_TILES * 16);
    int*    n_tiles   = (int*)   alloc(4);

    prep_kernel<<<3584, 256, 0, stream>>>(We, WeT, x, Wg, e2, w2, Abf, out);
    route_kernel<<<8, 256, 0, stream>>>(e2, w2, token_list, w_s, tile_desc, n_tiles);
    moe_gemm<<<dim3(8, MAX_TILES), 256, 0, stream>>>(Abf, WeT, token_list, w_s,
                                                     tile_desc, n_tiles, out);
}

// Round 12
// 109.260 us; speedup vs baseline: 1.6419x; 1.6419x over previous
//
#include <hip/hip_runtime.h>
#include <hip/hip_bf16.h>
#include <stdint.h>

#define NTOK 8192
#define D_   1024
#define E_   8
#define MT   128
#define NT   128
#define BK   64
#define KSTEPS 32     // 16 per expert half
#define MAX_TILES 96
#define BUF_S 16384   // shorts per buffer: A 128*64 + B 128*64

typedef __attribute__((ext_vector_type(8))) short short8;
typedef __attribute__((ext_vector_type(4))) float f32x4;

__device__ inline unsigned short f2b(float f) {
    unsigned int u = __float_as_uint(f);
    unsigned int r = (u + 0x7fffu + ((u >> 16) & 1u)) >> 16;
    return (unsigned short)r;
}

// async global->LDS, 16B per lane; LDS dest = wave-uniform base + lane*16.
__device__ inline void gload16(const void* g, void* l) {
    __builtin_amdgcn_global_load_lds(
        (const __attribute__((address_space(1))) unsigned int*)(uintptr_t)g,
        (__attribute__((address_space(3))) unsigned int*)(unsigned int)(uintptr_t)l,
        16, 0, 0);
}

// ---------------- Phase 0+1 fused: gating+cast (blocks 0..1023, FIRST) || We transpose (1024..3071) ----------------
__global__ __launch_bounds__(256) void prep_kernel(const float* __restrict__ We,
                                                   unsigned short* __restrict__ WeT,
                                                   const float* __restrict__ x,
                                                   const float* __restrict__ Wg,
                                                   int* __restrict__ g_tok,
                                                   float* __restrict__ wA_tok,
                                                   float* __restrict__ wB_tok,
                                                   unsigned short* __restrict__ Abf) {
    __shared__ __align__(16) float smem[8192];   // overlay: 8x1024 wgt | 64x65 tile
    int b = blockIdx.x;
    int t = threadIdx.x;
    if (b < 1024) {
        // ---- gating + unweighted bf16 cast; 8 tokens per block, 2 per wave ----
        float* wgt = smem;   // transposed: wgt[e*1024 + d]
        for (int i = t; i < 8192; i += 256) wgt[(i & 7) * 1024 + (i >> 3)] = Wg[i];
        __syncthreads();
        int wave = t >> 6, lane = t & 63;
        int tok0 = b * 8 + wave * 2;

        for (int tki = 0; tki < 2; tki++) {
            int tok = tok0 + tki;
            const float* xr = x + (size_t)tok * D_;

            float4 xv[4];
            float acc[8] = {0.f, 0.f, 0.f, 0.f, 0.f, 0.f, 0.f, 0.f};
            #pragma unroll
            for (int i = 0; i < 4; i++) {
                int d0 = i * 256 + lane * 4;
                xv[i] = *reinterpret_cast<const float4*>(xr + d0);
                #pragma unroll
                for (int e = 0; e < 8; e++) {
                    float4 w = *reinterpret_cast<const float4*>(&wgt[e * 1024 + d0]);
                    acc[e] += xv[i].x * w.x + xv[i].y * w.y + xv[i].z * w.z + xv[i].w * w.w;
                }
            }
            #pragma unroll
            for (int e = 0; e < 8; e++)
                #pragma unroll
                for (int off = 32; off > 0; off >>= 1)
                    acc[e] += __shfl_xor(acc[e], off, 64);

            float best = acc[0]; int bi = 0;
            #pragma unroll
            for (int e = 1; e < 8; e++) { if (acc[e] > best) { best = acc[e]; bi = e; } }
            float second = -3.4e38f; int si = 0;
            #pragma unroll
            for (int e = 0; e < 8; e++) { if (e != bi && acc[e] > second) { second = acc[e]; si = e; } }
            float eb = __expf(second - best);
            eb = fmaxf(eb, 1e-20f);
            float w0 = 1.f / (1.f + eb);
            float w1 = eb / (1.f + eb);
            int ea, ebx; float wA, wB;
            if (bi < si) { ea = bi; ebx = si; wA = w0; wB = w1; }
            else         { ea = si; ebx = bi; wA = w1; wB = w0; }
            if (lane == 0) {
                g_tok[tok] = ea * 8 + ebx;
                wA_tok[tok] = wA;
                wB_tok[tok] = wB;
            }

            unsigned short* rowp = Abf + (size_t)tok * D_;
            #pragma unroll
            for (int i = 0; i < 4; i++) {
                int d0 = i * 256 + lane * 4;
                uint2 p;
                p.x = (unsigned)f2b(xv[i].x) | ((unsigned)f2b(xv[i].y) << 16);
                p.y = (unsigned)f2b(xv[i].z) | ((unsigned)f2b(xv[i].w) << 16);
                *reinterpret_cast<uint2*>(rowp + d0) = p;
            }
        }
    } else {
        // ---- We (E,D,D) f32 -> WeT (E,M,D) bf16 ----
        float (*tile)[65] = reinterpret_cast<float (*)[65]>(smem);
        int bb = b - 1024;
        int e = bb >> 8, rem = bb & 255;
        int m0 = (rem & 15) * 64, d0 = (rem >> 4) * 64;
        const float* src = We + ((size_t)e << 20);
        int r = t >> 4, c4 = (t & 15) * 4;
        #pragma unroll
        for (int i = 0; i < 4; i++) {
            int d = r + i * 16;
            float4 v = *reinterpret_cast<const float4*>(src + (size_t)(d0 + d) * D_ + m0 + c4);
            tile[d][c4 + 0] = v.x; tile[d][c4 + 1] = v.y;
            tile[d][c4 + 2] = v.z; tile[d][c4 + 3] = v.w;
        }
        __syncthreads();
        int m = t >> 2, dq = (t & 3) * 16;
        unsigned int pack[8];
        #pragma unroll
        for (int j = 0; j < 16; j += 2) {
            pack[j >> 1] = (unsigned int)f2b(tile[dq + j][m]) |
                           ((unsigned int)f2b(tile[dq + j + 1][m]) << 16);
        }
        uint4* dst = reinterpret_cast<uint4*>(WeT + ((size_t)e << 20) + (size_t)(m0 + m) * D_ + d0 + dq);
        dst[0] = make_uint4(pack[0], pack[1], pack[2], pack[3]);
        dst[1] = make_uint4(pack[4], pack[5], pack[6], pack[7]);
    }
}

// ---------------- Phase 2: routing — 64 parallel blocks, mixed 128/64 tiles ----------------
__global__ __launch_bounds__(256) void route_kernel(const int* __restrict__ g_tok,
                                                    const float* __restrict__ wA_tok,
                                                    const float* __restrict__ wB_tok,
                                                    int* __restrict__ token_list,
                                                    float* __restrict__ wA_s,
                                                    float* __restrict__ wB_s,
                                                    int4* __restrict__ tile_desc,
                                                    int* __restrict__ n_tiles_out) {
    int g = blockIdx.x;    // 0..63
    int t = threadIdx.x;   // 0..255
    __shared__ int cnt[64];
    __shared__ int pfx[256];
    __shared__ int startg, tbase, tottiles;
    if (t < 64) cnt[t] = 0;
    __syncthreads();

    int base = t * 32;
    int gl[32];
    int my = 0;
    #pragma unroll
    for (int k = 0; k < 32; k++) {
        gl[k] = g_tok[base + k];
        my += (gl[k] == g);
    }
    #pragma unroll
    for (int k = 0; k < 32; k++) atomicAdd(&cnt[gl[k]], 1);
    pfx[t] = my;
    __syncthreads();

    if (t == 0) {
        int run = 0, tb = 0, tt = 0;
        for (int gg = 0; gg < 64; gg++) {
            int c = cnt[gg];
            int n = 0, rem = c;
            while (rem > 64) { int take = (rem >= 128) ? 128 : rem; rem -= take; n++; }
            if (rem > 0) n++;
            if (gg < g) { run += c; tb += n; }
            tt += n;
        }
        startg = run; tbase = tb; tottiles = tt;
    }
    for (int off = 1; off < 256; off <<= 1) {
        int add = (t >= off) ? pfx[t - off] : 0;
        __syncthreads();
        pfx[t] += add;
        __syncthreads();
    }

    int pos = startg + pfx[t] - my;
    #pragma unroll
    for (int k = 0; k < 32; k++) {
        if (gl[k] == g) {
            int idx = base + k;
            token_list[pos] = idx;
            wA_s[pos] = wA_tok[idx];
            wB_s[pos] = wB_tok[idx];
            pos++;
        }
    }
    if (t == 0) {
        int rem = cnt[g], off2 = 0, ti = tbase;
        while (rem > 64) {
            int take = (rem >= 128) ? 128 : rem;
            tile_desc[ti++] = make_int4(startg + off2, take, g >> 3, g & 7);
            off2 += take; rem -= take;
        }
        if (rem > 0) tile_desc[ti++] = make_int4(startg + off2, rem, g >> 3, g & 7);
        if (g == 0) *n_tiles_out = tottiles;
    }
}

// ---------------- Phase 3: grouped GEMM — 128x128, BK=64, DOUBLE-buffer + counted vmcnt ----------------
// Grid dim3(8, tiles): XCD = colblk -> per-XCD B slice = 2 MB (L2-resident).
// ks 0..15: expert ea; ks 16..31: expert ebx over SAME A (acc rescaled by wA/wB at switch, *wB at end).
// Schedule per iter: stage(ks+1, buf^1) -> vmcnt(8) [stage(ks) done, ks+1 in flight] -> barrier
// -> MFMA(buf) -> barrier (WAR safety for next stage).
__global__ __launch_bounds__(256, 2) void moe_gemm(const unsigned short* __restrict__ Abf,
                                                   const unsigned short* __restrict__ WeT,
                                                   const int* __restrict__ token_list,
                                                   const float* __restrict__ wA_s,
                                                   const float* __restrict__ wB_s,
                                                   const int4* __restrict__ tile_desc,
                                                   const int* __restrict__ n_tiles,
                                                   float* __restrict__ out) {
    int tile = blockIdx.y;
    if (tile >= *n_tiles) return;
    int4 dsc = tile_desc[tile];
    int loff = dsc.x, rows = dsc.y, ea = dsc.z, ebx = dsc.w;
    int ncol0 = blockIdx.x * NT;

    __shared__ __align__(16) unsigned short lds[2 * BUF_S];  // 64 KB
    __shared__ int tokOut[MT];
    __shared__ int tokStage[MT];
    __shared__ float rat[MT], wBsh[MT];

    int t = threadIdx.x;
    int wave = t >> 6, lane = t & 63;

    if (t < MT) {
        int idx = loff + ((t < rows) ? t : 0);
        int tk = token_list[idx];
        tokStage[t] = tk;
        tokOut[t] = (t < rows) ? tk : -1;
        float wa = wA_s[idx], wb = wB_s[idx];
        wBsh[t] = wb;
        rat[t] = wa / fmaxf(wb, 1e-30f);
    }
    __syncthreads();

    const unsigned short* wbase = WeT + ((size_t)ea << 20);
    size_t ebd = ((size_t)(ebx - ea)) << 20;
    int l15 = lane & 15, hi = lane >> 4, q4 = hi * 4;

    if (rows > 64) {
        // ================= FULL PATH: 128x128, wave-tile 64x64 =================
        const unsigned short* asrc[4];
        const unsigned short* bsrc[4];
        #pragma unroll
        for (int i = 0; i < 4; i++) {
            int g = t + i * 256;
            int row = g >> 3;
            int c = (g & 7) ^ (row & 7);
            asrc[i] = Abf + (size_t)tokStage[row] * D_ + c * 8;
            bsrc[i] = wbase + (size_t)(ncol0 + row) * D_ + c * 8;
        }

        auto stage = [&](int ks, int buf) {
            int k0 = (ks & 15) * BK;
            size_t bo = (size_t)k0 + ((ks < 16) ? 0 : ebd);
            unsigned short* base = &lds[buf * BUF_S];
            #pragma unroll
            for (int i = 0; i < 4; i++) {
                int dbase = (i * 256 + wave * 64) * 8;
                gload16(asrc[i] + k0, base + dbase);
                gload16(bsrc[i] + bo, base + 8192 + dbase);
            }
        };

        int wm = (wave >> 1) * 64, wn = (wave & 1) * 64;
        int aoff[2][4], boff[2][4];
        #pragma unroll
        for (int ksub = 0; ksub < 2; ksub++) {
            #pragma unroll
            for (int m = 0; m < 4; m++) {
                int r = wm + m * 16 + l15;
                aoff[ksub][m] = r * BK + (((hi + 4 * ksub) ^ (r & 7)) << 3);
                int rb = wn + m * 16 + l15;
                boff[ksub][m] = 8192 + rb * BK + (((hi + 4 * ksub) ^ (rb & 7)) << 3);
            }
        }

        f32x4 acc[4][4];
        #pragma unroll
        for (int m = 0; m < 4; m++)
            #pragma unroll
            for (int n = 0; n < 4; n++) acc[m][n] = (f32x4){0.f, 0.f, 0.f, 0.f};

        stage(0, 0);
        int cur = 0;
        for (int ks = 0; ks < KSTEPS; ++ks) {
            if (ks < KSTEPS - 1) {
                stage(ks + 1, cur ^ 1);
                asm volatile("s_waitcnt vmcnt(8)" ::: "memory");
            } else {
                asm volatile("s_waitcnt vmcnt(0)" ::: "memory");
            }
            __builtin_amdgcn_s_barrier();
            if (ks == 16) {
                #pragma unroll
                for (int m = 0; m < 4; m++) {
                    #pragma unroll
                    for (int j = 0; j < 4; j++) {
                        float rr = rat[wm + m * 16 + q4 + j];
                        #pragma unroll
                        for (int n = 0; n < 4; n++) acc[m][n][j] *= rr;
                    }
                }
            }
            const unsigned short* Ab = &lds[cur * BUF_S];
            #pragma unroll
            for (int ksub = 0; ksub < 2; ++ksub) {
                short8 a[4], bfr[4];
                #pragma unroll
                for (int m = 0; m < 4; m++) {
                    a[m] = *reinterpret_cast<const short8*>(&Ab[aoff[ksub][m]]);
                    bfr[m] = *reinterpret_cast<const short8*>(&Ab[boff[ksub][m]]);
                }
                #pragma unroll
                for (int m = 0; m < 4; m++)
                    #pragma unroll
                    for (int n = 0; n < 4; n++)
                        acc[m][n] = __builtin_amdgcn_mfma_f32_16x16x32_bf16(a[m], bfr[n], acc[m][n], 0, 0, 0);
            }
            __builtin_amdgcn_s_barrier();
            cur ^= 1;
        }

        #pragma unroll
        for (int m = 0; m < 4; m++) {
            #pragma unroll
            for (int n = 0; n < 4; n++) {
                int col = ncol0 + wn + n * 16 + l15;
                #pragma unroll
                for (int j = 0; j < 4; j++) {
                    int r = wm + m * 16 + q4 + j;
                    int tk = tokOut[r];
                    if (tk >= 0) out[(size_t)tk * D_ + col] = acc[m][n][j] * wBsh[r];
                }
            }
        }
    } else {
        // ================= TAIL PATH: 64x128, wave-tile 32x64 =================
        const unsigned short* asrcT[2];
        const unsigned short* bsrcT[4];
        #pragma unroll
        for (int i = 0; i < 2; i++) {
            int g = t + i * 256;
            int row = g >> 3;
            int c = (g & 7) ^ (row & 7);
            asrcT[i] = Abf + (size_t)tokStage[row] * D_ + c * 8;
        }
        #pragma unroll
        for (int i = 0; i < 4; i++) {
            int g = t + i * 256;
            int row = g >> 3;
            int c = (g & 7) ^ (row & 7);
            bsrcT[i] = wbase + (size_t)(ncol0 + row) * D_ + c * 8;
        }

        auto stageT = [&](int ks, int buf) {
            int k0 = (ks & 15) * BK;
            size_t bo = (size_t)k0 + ((ks < 16) ? 0 : ebd);
            unsigned short* base = &lds[buf * BUF_S];
            #pragma unroll
            for (int i = 0; i < 2; i++)
                gload16(asrcT[i] + k0, base + (i * 256 + wave * 64) * 8);
            #pragma unroll
            for (int i = 0; i < 4; i++)
                gload16(bsrcT[i] + bo, base + 4096 + (i * 256 + wave * 64) * 8);
        };

        int wm = (wave >> 1) * 32, wn = (wave & 1) * 64;
        int aoff[2][2], boff[2][4];
        #pragma unroll
        for (int ksub = 0; ksub < 2; ksub++) {
            #pragma unroll
            for (int m = 0; m < 2; m++) {
                int r = wm + m * 16 + l15;
                aoff[ksub][m] = r * BK + (((hi + 4 * ksub) ^ (r & 7)) << 3);
            }
            #pragma unroll
            for (int n = 0; n < 4; n++) {
                int rb = wn + n * 16 + l15;
                boff[ksub][n] = 4096 + rb * BK + (((hi + 4 * ksub) ^ (rb & 7)) << 3);
            }
        }

        f32x4 acc[2][4];
        #pragma unroll
        for (int m = 0; m < 2; m++)
            #pragma unroll
            for (int n = 0; n < 4; n++) acc[m][n] = (f32x4){0.f, 0.f, 0.f, 0.f};

        stageT(0, 0);
        int cur = 0;
        for (int ks = 0; ks < KSTEPS; ++ks) {
            if (ks < KSTEPS - 1) {
                stageT(ks + 1, cur ^ 1);
                asm volatile("s_waitcnt vmcnt(6)" ::: "memory");
            } else {
                asm volatile("s_waitcnt vmcnt(0)" ::: "memory");
            }
            __builtin_amdgcn_s_barrier();
            if (ks == 16) {
                #pragma unroll
                for (int m = 0; m < 2; m++) {
                    #pragma unroll
                    for (int j = 0; j < 4; j++) {
                        float rr = rat[wm + m * 16 + q4 + j];
                        #pragma unroll
                        for (int n = 0; n < 4; n++) acc[m][n][j] *= rr;
                    }
                }
            }
            const unsigned short* Ab = &lds[cur * BUF_S];
            #pragma unroll
            for (int ksub = 0; ksub < 2; ++ksub) {
                short8 a[2], bfr[4];
                #pragma unroll
                for (int m = 0; m < 2; m++)
                    a[m] = *reinterpret_cast<const short8*>(&Ab[aoff[ksub][m]]);
                #pragma unroll
                for (int n = 0; n < 4; n++)
                    bfr[n] = *reinterpret_cast<const short8*>(&Ab[boff[ksub][n]]);
                #pragma unroll
                for (int m = 0; m < 2; m++)
                    #pragma unroll
                    for (int n = 0; n < 4; n++)
                        acc[m][n] = __builtin_amdgcn_mfma_f32_16x16x32_bf16(a[m], bfr[n], acc[m][n], 0, 0, 0);
            }
            __builtin_amdgcn_s_barrier();
            cur ^= 1;
        }

        #pragma unroll
        for (int m = 0; m < 2; m++) {
            #pragma unroll
            for (int n = 0; n < 4; n++) {
                int col = ncol0 + wn + n * 16 + l15;
                #pragma unroll
                for (int j = 0; j < 4; j++) {
                    int r = wm + m * 16 + q4 + j;
                    int tk = tokOut[r];
                    if (tk >= 0) out[(size_t)tk * D_ + col] = acc[m][n][j] * wBsh[r];
                }
            }
        }
    }
}

extern "C" void kernel_launch(void* const* d_in, const int* in_sizes, int n_in,
                              void* d_out, int out_size, void* d_ws, size_t ws_size,
                              hipStream_t stream) {
    const float* x  = (const float*)d_in[0];
    const float* Wg = (const float*)d_in[1];
    const float* We = (const float*)d_in[2];
    float* out = (float*)d_out;

    size_t off = 0;
    auto alloc = [&](size_t bytes) -> void* {
        void* p = (char*)d_ws + off;
        off += (bytes + 255) & ~(size_t)255;
        return p;
    };
    unsigned short* WeT  = (unsigned short*)alloc((size_t)E_ * 1024 * 1024 * 2);  // 16 MB
    unsigned short* Abf  = (unsigned short*)alloc((size_t)NTOK * D_ * 2);         // 16.8 MB
    int*   g_tok      = (int*)  alloc(NTOK * 4);
    float* wA_tok     = (float*)alloc(NTOK * 4);
    float* wB_tok     = (float*)alloc(NTOK * 4);
    int*   token_list = (int*)  alloc(NTOK * 4);
    float* wA_s       = (float*)alloc(NTOK * 4);
    float* wB_s       = (float*)alloc(NTOK * 4);
    int4*  tile_desc  = (int4*) alloc(MAX_TILES * 16);
    int*   n_tiles    = (int*)  alloc(4);

    prep_kernel<<<1024 + 2048, 256, 0, stream>>>(We, WeT, x, Wg, g_tok, wA_tok, wB_tok, Abf);
    route_kernel<<<64, 256, 0, stream>>>(g_tok, wA_tok, wB_tok,
                                         token_list, wA_s, wB_s, tile_desc, n_tiles);
    moe_gemm<<<dim3(8, MAX_TILES), 256, 0, stream>>>(Abf, WeT, token_list, wA_s, wB_s,
                                                     tile_desc, n_tiles, out);
}

// Round 13
// 108.145 us; speedup vs baseline: 1.6589x; 1.0103x over previous
//
#include <hip/hip_runtime.h>
#include <hip/hip_bf16.h>
#include <stdint.h>

#define NTOK 8192
#define D_   1024
#define E_   8
#define MT   64
#define NT   128
#define BK   64
#define KSTEPS 32     // 16 per expert half
#define MAX_TILES 192
#define BUF_S 12288   // shorts per LDS buffer: A 64*64=4096 + B 128*64=8192

typedef __attribute__((ext_vector_type(8))) short short8;
typedef __attribute__((ext_vector_type(4))) float f32x4;

__device__ inline unsigned short f2b(float f) {
    unsigned int u = __float_as_uint(f);
    unsigned int r = (u + 0x7fffu + ((u >> 16) & 1u)) >> 16;
    return (unsigned short)r;
}

// async global->LDS, 16B per lane; LDS dest = wave-uniform base + lane*16.
__device__ inline void gload16(const void* g, void* l) {
    __builtin_amdgcn_global_load_lds(
        (const __attribute__((address_space(1))) unsigned int*)(uintptr_t)g,
        (__attribute__((address_space(3))) unsigned int*)(unsigned int)(uintptr_t)l,
        16, 0, 0);
}

// ---------------- Phase 0+1 fused: gating+cast (blocks 0..1023, FIRST) || We transpose (1024..3071) ----------------
__global__ __launch_bounds__(256) void prep_kernel(const float* __restrict__ We,
                                                   unsigned short* __restrict__ WeT,
                                                   const float* __restrict__ x,
                                                   const float* __restrict__ Wg,
                                                   int* __restrict__ g_tok,
                                                   float* __restrict__ wA_tok,
                                                   float* __restrict__ wB_tok,
                                                   unsigned short* __restrict__ Abf) {
    __shared__ __align__(16) float smem[8192];   // overlay: 8x1024 wgt | 64x65 tile
    int b = blockIdx.x;
    int t = threadIdx.x;
    if (b < 1024) {
        // ---- gating + unweighted bf16 cast; 8 tokens per block, 2 per wave ----
        float* wgt = smem;   // transposed: wgt[e*1024 + d]
        for (int i = t; i < 8192; i += 256) wgt[(i & 7) * 1024 + (i >> 3)] = Wg[i];
        __syncthreads();
        int wave = t >> 6, lane = t & 63;
        int tok0 = b * 8 + wave * 2;

        for (int tki = 0; tki < 2; tki++) {
            int tok = tok0 + tki;
            const float* xr = x + (size_t)tok * D_;

            float4 xv[4];
            float acc[8] = {0.f, 0.f, 0.f, 0.f, 0.f, 0.f, 0.f, 0.f};
            #pragma unroll
            for (int i = 0; i < 4; i++) {
                int d0 = i * 256 + lane * 4;
                xv[i] = *reinterpret_cast<const float4*>(xr + d0);
                #pragma unroll
                for (int e = 0; e < 8; e++) {
                    float4 w = *reinterpret_cast<const float4*>(&wgt[e * 1024 + d0]);
                    acc[e] += xv[i].x * w.x + xv[i].y * w.y + xv[i].z * w.z + xv[i].w * w.w;
                }
            }
            #pragma unroll
            for (int e = 0; e < 8; e++)
                #pragma unroll
                for (int off = 32; off > 0; off >>= 1)
                    acc[e] += __shfl_xor(acc[e], off, 64);

            float best = acc[0]; int bi = 0;
            #pragma unroll
            for (int e = 1; e < 8; e++) { if (acc[e] > best) { best = acc[e]; bi = e; } }
            float second = -3.4e38f; int si = 0;
            #pragma unroll
            for (int e = 0; e < 8; e++) { if (e != bi && acc[e] > second) { second = acc[e]; si = e; } }
            float eb = __expf(second - best);
            eb = fmaxf(eb, 1e-20f);
            float w0 = 1.f / (1.f + eb);
            float w1 = eb / (1.f + eb);
            int ea, ebx; float wA, wB;
            if (bi < si) { ea = bi; ebx = si; wA = w0; wB = w1; }
            else         { ea = si; ebx = bi; wA = w1; wB = w0; }
            if (lane == 0) {
                g_tok[tok] = ea * 8 + ebx;
                wA_tok[tok] = wA;
                wB_tok[tok] = wB;
            }

            unsigned short* rowp = Abf + (size_t)tok * D_;
            #pragma unroll
            for (int i = 0; i < 4; i++) {
                int d0 = i * 256 + lane * 4;
                uint2 p;
                p.x = (unsigned)f2b(xv[i].x) | ((unsigned)f2b(xv[i].y) << 16);
                p.y = (unsigned)f2b(xv[i].z) | ((unsigned)f2b(xv[i].w) << 16);
                *reinterpret_cast<uint2*>(rowp + d0) = p;
            }
        }
    } else {
        // ---- We (E,D,D) f32 -> WeT (E,M,D) bf16 ----
        float (*tile)[65] = reinterpret_cast<float (*)[65]>(smem);
        int bb = b - 1024;
        int e = bb >> 8, rem = bb & 255;
        int m0 = (rem & 15) * 64, d0 = (rem >> 4) * 64;
        const float* src = We + ((size_t)e << 20);
        int r = t >> 4, c4 = (t & 15) * 4;
        #pragma unroll
        for (int i = 0; i < 4; i++) {
            int d = r + i * 16;
            float4 v = *reinterpret_cast<const float4*>(src + (size_t)(d0 + d) * D_ + m0 + c4);
            tile[d][c4 + 0] = v.x; tile[d][c4 + 1] = v.y;
            tile[d][c4 + 2] = v.z; tile[d][c4 + 3] = v.w;
        }
        __syncthreads();
        int m = t >> 2, dq = (t & 3) * 16;
        unsigned int pack[8];
        #pragma unroll
        for (int j = 0; j < 16; j += 2) {
            pack[j >> 1] = (unsigned int)f2b(tile[dq + j][m]) |
                           ((unsigned int)f2b(tile[dq + j + 1][m]) << 16);
        }
        uint4* dst = reinterpret_cast<uint4*>(WeT + ((size_t)e << 20) + (size_t)(m0 + m) * D_ + d0 + dq);
        dst[0] = make_uint4(pack[0], pack[1], pack[2], pack[3]);
        dst[1] = make_uint4(pack[4], pack[5], pack[6], pack[7]);
    }
}

// ---------------- Phase 2: routing — 64 parallel blocks, uniform 64-row tiles ----------------
__global__ __launch_bounds__(256) void route_kernel(const int* __restrict__ g_tok,
                                                    const float* __restrict__ wA_tok,
                                                    const float* __restrict__ wB_tok,
                                                    int* __restrict__ token_list,
                                                    float* __restrict__ wA_s,
                                                    float* __restrict__ wB_s,
                                                    int4* __restrict__ tile_desc,
                                                    int* __restrict__ n_tiles_out) {
    int g = blockIdx.x;    // 0..63
    int t = threadIdx.x;   // 0..255
    __shared__ int cnt[64];
    __shared__ int pfx[256];
    __shared__ int startg, tbase, tottiles;
    if (t < 64) cnt[t] = 0;
    __syncthreads();

    int base = t * 32;
    int gl[32];
    int my = 0;
    #pragma unroll
    for (int k = 0; k < 32; k++) {
        gl[k] = g_tok[base + k];
        my += (gl[k] == g);
    }
    #pragma unroll
    for (int k = 0; k < 32; k++) atomicAdd(&cnt[gl[k]], 1);
    pfx[t] = my;
    __syncthreads();

    if (t == 0) {
        int run = 0, tb = 0, tt = 0;
        for (int gg = 0; gg < 64; gg++) {
            int c = cnt[gg];
            int n = (c + MT - 1) / MT;
            if (gg < g) { run += c; tb += n; }
            tt += n;
        }
        startg = run; tbase = tb; tottiles = tt;
    }
    for (int off = 1; off < 256; off <<= 1) {
        int add = (t >= off) ? pfx[t - off] : 0;
        __syncthreads();
        pfx[t] += add;
        __syncthreads();
    }

    int pos = startg + pfx[t] - my;
    #pragma unroll
    for (int k = 0; k < 32; k++) {
        if (gl[k] == g) {
            int idx = base + k;
            token_list[pos] = idx;
            wA_s[pos] = wA_tok[idx];
            wB_s[pos] = wB_tok[idx];
            pos++;
        }
    }
    if (t == 0) {
        int rem = cnt[g], off2 = 0, ti = tbase;
        while (rem > 0) {
            int take = (rem < MT) ? rem : MT;
            tile_desc[ti++] = make_int4(startg + off2, take, g >> 3, g & 7);
            off2 += take; rem -= take;
        }
        if (g == 0) *n_tiles_out = tottiles;
    }
}

// ---------------- Phase 3: grouped GEMM — R6 schedule, 2 sequential col-phases per block ----------------
// Grid dim3(4, tiles): each block covers cols [x*256, x*256+256) via 2 phases of 128.
// A read by only 4 XCDs (fetch 134->67 MB); per-XCD B slice = 4 MB.
// Per phase: ks 0..15 expert ea, 16..31 expert ebx over same A (rescale at switch, *wB at end).
__global__ __launch_bounds__(256, 2) void moe_gemm(const unsigned short* __restrict__ Abf,
                                                   const unsigned short* __restrict__ WeT,
                                                   const int* __restrict__ token_list,
                                                   const float* __restrict__ wA_s,
                                                   const float* __restrict__ wB_s,
                                                   const int4* __restrict__ tile_desc,
                                                   const int* __restrict__ n_tiles,
                                                   float* __restrict__ out) {
    int tile = blockIdx.y;
    if (tile >= *n_tiles) return;
    int4 dsc = tile_desc[tile];
    int loff = dsc.x, rows = dsc.y, ea = dsc.z, ebx = dsc.w;

    __shared__ __align__(16) unsigned short lds[2 * BUF_S];  // 48 KB
    __shared__ int tokOut[MT];
    __shared__ int tokStage[MT];
    __shared__ float rat[MT], wBsh[MT];

    int t = threadIdx.x;
    int wave = t >> 6, lane = t & 63;

    if (t < MT) {
        int idx = loff + ((t < rows) ? t : 0);
        int tk = token_list[idx];
        tokStage[t] = tk;
        tokOut[t] = (t < rows) ? tk : -1;
        float wa = wA_s[idx], wb = wB_s[idx];
        wBsh[t] = wb;
        rat[t] = wa / fmaxf(wb, 1e-30f);
    }
    __syncthreads();

    // staging sources (swizzle folded into global address; LDS dest linear)
    int swz8 = (((t & 7) ^ ((t >> 3) & 7)) << 3);
    const unsigned short* asrc0 = Abf + (size_t)tokStage[t >> 3] * D_ + swz8;
    const unsigned short* asrc1 = Abf + (size_t)tokStage[32 + (t >> 3)] * D_ + swz8;
    const unsigned short* wbase = WeT + ((size_t)ea << 20);
    size_t ebd = ((size_t)(ebx - ea)) << 20;

    // wave grid 2(M) x 2(N); wave-tile 32x64  (R6-verified layout)
    int wm = (wave >> 1) * 32, wn = (wave & 1) * 64;
    int l15 = lane & 15, hi = lane >> 4, lo7 = lane & 7;
    int rA0 = (wm + l15) * BK;
    int rA1 = rA0 + 16 * BK;
    int cB0 = (wn + l15) * BK + 4096;
    int s0 = (hi ^ lo7) << 3;            // ksub 0 phys slot offset (shorts)
    int s1 = ((4 + hi) ^ lo7) << 3;      // ksub 1
    int q4 = hi * 4;
    int wu = wave * 512;                 // wave-uniform chunk base (shorts)

    for (int cp = 0; cp < 2; ++cp) {
        int ncol0 = (blockIdx.x * 2 + cp) * NT;
        const unsigned short* bsrc0 = wbase + (size_t)(ncol0 +  0 + (t >> 3)) * D_ + swz8;
        const unsigned short* bsrc1 = wbase + (size_t)(ncol0 + 32 + (t >> 3)) * D_ + swz8;
        const unsigned short* bsrc2 = wbase + (size_t)(ncol0 + 64 + (t >> 3)) * D_ + swz8;
        const unsigned short* bsrc3 = wbase + (size_t)(ncol0 + 96 + (t >> 3)) * D_ + swz8;

        auto stage = [&](int ks, int buf) {
            unsigned short* base = &lds[buf * BUF_S];
            int k0 = (ks & 15) * BK;
            size_t boff = (size_t)k0 + ((ks < 16) ? 0 : ebd);
            gload16(asrc0 + k0,   base + wu);
            gload16(asrc1 + k0,   base + 2048 + wu);
            gload16(bsrc0 + boff, base + 4096 + wu);
            gload16(bsrc1 + boff, base + 6144 + wu);
            gload16(bsrc2 + boff, base + 8192 + wu);
            gload16(bsrc3 + boff, base + 10240 + wu);
        };

        f32x4 acc[2][4];
        #pragma unroll
        for (int m = 0; m < 2; m++)
            #pragma unroll
            for (int n = 0; n < 4; n++) acc[m][n] = (f32x4){0.f, 0.f, 0.f, 0.f};

        stage(0, 0);
        for (int ks = 0; ks < KSTEPS; ++ks) {
            if (ks < KSTEPS - 1) {
                stage(ks + 1, (ks + 1) & 1);
                asm volatile("s_waitcnt vmcnt(6)" ::: "memory");
            } else {
                asm volatile("s_waitcnt vmcnt(0)" ::: "memory");
            }
            __builtin_amdgcn_s_barrier();
            if (ks == 16) {
                // expert switch: acc *= wA/wB per row; epilogue multiplies by wB
                #pragma unroll
                for (int m = 0; m < 2; m++) {
                    #pragma unroll
                    for (int j = 0; j < 4; j++) {
                        float rr = rat[wm + m * 16 + q4 + j];
                        #pragma unroll
                        for (int n = 0; n < 4; n++) acc[m][n][j] *= rr;
                    }
                }
            }
            const unsigned short* Ab = &lds[(ks & 1) * BUF_S];
            #pragma unroll
            for (int ksub = 0; ksub < 2; ++ksub) {
                int s = ksub ? s1 : s0;
                short8 a0 = *reinterpret_cast<const short8*>(&Ab[rA0 + s]);
                short8 a1 = *reinterpret_cast<const short8*>(&Ab[rA1 + s]);
                #pragma unroll
                for (int n = 0; n < 4; n++) {
                    short8 bfr = *reinterpret_cast<const short8*>(&Ab[cB0 + n * (16 * BK) + s]);
                    acc[0][n] = __builtin_amdgcn_mfma_f32_16x16x32_bf16(a0, bfr, acc[0][n], 0, 0, 0);
                    acc[1][n] = __builtin_amdgcn_mfma_f32_16x16x32_bf16(a1, bfr, acc[1][n], 0, 0, 0);
                }
            }
            __builtin_amdgcn_s_barrier();   // readers done before next stage overwrites other buffer
        }

        // epilogue for this col-phase: single writer per out element; out = acc * wB
        #pragma unroll
        for (int m = 0; m < 2; m++) {
            #pragma unroll
            for (int n = 0; n < 4; n++) {
                int col = ncol0 + wn + n * 16 + l15;
                #pragma unroll
                for (int j = 0; j < 4; j++) {
                    int r = wm + m * 16 + q4 + j;
                    int tk = tokOut[r];
                    if (tk >= 0) out[(size_t)tk * D_ + col] = acc[m][n][j] * wBsh[r];
                }
            }
        }
    }
}

extern "C" void kernel_launch(void* const* d_in, const int* in_sizes, int n_in,
                              void* d_out, int out_size, void* d_ws, size_t ws_size,
                              hipStream_t stream) {
    const float* x  = (const float*)d_in[0];
    const float* Wg = (const float*)d_in[1];
    const float* We = (const float*)d_in[2];
    float* out = (float*)d_out;

    size_t off = 0;
    auto alloc = [&](size_t bytes) -> void* {
        void* p = (char*)d_ws + off;
        off += (bytes + 255) & ~(size_t)255;
        return p;
    };
    unsigned short* WeT  = (unsigned short*)alloc((size_t)E_ * 1024 * 1024 * 2);  // 16 MB
    unsigned short* Abf  = (unsigned short*)alloc((size_t)NTOK * D_ * 2);         // 16.8 MB
    int*   g_tok      = (int*)  alloc(NTOK * 4);
    float* wA_tok     = (float*)alloc(NTOK * 4);
    float* wB_tok     = (float*)alloc(NTOK * 4);
    int*   token_list = (int*)  alloc(NTOK * 4);
    float* wA_s       = (float*)alloc(NTOK * 4);
    float* wB_s       = (float*)alloc(NTOK * 4);
    int4*  tile_desc  = (int4*) alloc(MAX_TILES * 16);
    int*   n_tiles    = (int*)  alloc(4);

    prep_kernel<<<1024 + 2048, 256, 0, stream>>>(We, WeT, x, Wg, g_tok, wA_tok, wB_tok, Abf);
    route_kernel<<<64, 256, 0, stream>>>(g_tok, wA_tok, wB_tok,
                                         token_list, wA_s, wB_s, tile_desc, n_tiles);
    moe_gemm<<<dim3(4, MAX_TILES), 256, 0, stream>>>(Abf, WeT, token_list, wA_s, wB_s,
                                                     tile_desc, n_tiles, out);
}